// Round 11
// baseline (88.783 us; speedup 1.0000x reference)
//
#include <hip/hip_runtime.h>

#define BATCH 512
#define FEATURES 256
#define ENC 2048
#define HIDDEN 8192
#define CLASSES 1000
#define THRESH 16
#define MAXACT 256
#define NBLK1 256          // fused-z1 blocks (== CU count; 1/CU by LDS)
#define THR1 1024          // threads per fused block (16 waves)
#define ROWS_PER_BLK 32    // 8192 / 256
#define SLOTS 64

typedef unsigned long long u64;
typedef unsigned int u32;

// -------- workspace layout (bytes) --------
// cnts  : [0, 1024)             per-block pair count (written every call)
// pairs : [1024, 1024+65536)    NBLK1 x SLOTS u32 slots, entry (b<<13)|n
// Slot scheme is write-before-read => no zero-init, no memset node, and no
// cross-block sync anywhere (R4-R9: every in-kernel grid sync on MI355X is
// more expensive than a dispatch boundary; R6: tiny memset nodes cost 155us).
#define OFF_CNTS  0
#define OFF_PAIRS 1024

// Dispatch 1: fused encode + z1. Each block redundantly gray-encodes ALL of
// x into its own 128 KB LDS a0t (no prep dispatch, no sync), overlapped with
// the block's 256 KB W1 stream share (each wave preloads its full 2 rows =
// 16 float4 before encoding, so HBM latency hides under the VALU encode).
__global__ __launch_bounds__(THR1, 4) void z1_fused(
    const float* __restrict__ x, const float* __restrict__ W1,
    u32* __restrict__ cnts, u32* __restrict__ pairs)
{
    __shared__ u32 a0t[ENC * 16];          // 128 KB: col j, word w = batches 32w..
    __shared__ int colsAll[16][2][40];
    __shared__ int lcnt;

    int tid = threadIdx.x;
    int wv = tid >> 6, lane = tid & 63;
    int bid = blockIdx.x;
    if (tid == 0) lcnt = 0;

    // ---- issue the wave's full 2-row stream: 16 float4 in flight ----
    int n0 = bid * ROWS_PER_BLK + wv * 2;
    const float4* r0 = reinterpret_cast<const float4*>(W1 + (size_t)n0 * ENC);
    const float4* r1 = reinterpret_cast<const float4*>(W1 + (size_t)(n0 + 1) * ENC);
    float4 va[8], vb[8];
#pragma unroll
    for (int it = 0; it < 8; ++it) va[it] = r0[it * 64 + lane];
#pragma unroll
    for (int it = 0; it < 8; ++it) vb[it] = r1[it * 64 + lane];

    // ---- redundant encode into LDS (VALU; overlaps the loads above) ----
    // thread -> (w = tid&15, f = (tid>>4) + 64j, j<4); covers all 256x16 pairs
    {
        int w = tid & 15;
        int fbase = tid >> 4;              // 0..63
#pragma unroll
        for (int j = 0; j < 4; ++j) {
            int f = fbase + 64 * j;
            u32 m[8] = {0, 0, 0, 0, 0, 0, 0, 0};
#pragma unroll 4
            for (int i = 0; i < 32; ++i) {
                float v = x[(size_t)(w * 32 + i) * FEATURES + f];
                v = fminf(fmaxf(v, 0.0f), 1.0f);
                int lvl = (int)rintf(v * 255.0f);   // round-half-even == np.round
                int g = lvl ^ (lvl >> 1);
#pragma unroll
                for (int k = 0; k < 8; ++k)
                    m[k] |= (u32)((g >> k) & 1) << i;
            }
#pragma unroll
            for (int k = 0; k < 8; ++k)
                a0t[(f * 8 + k) * 16 + w] = m[k];
        }
    }

    // ---- compact the two rows to (col,sign) lists (first use of va/vb) ----
    u64 lmask = (lane == 63) ? 0x7fffffffffffffffULL : ((1ULL << lane) - 1ULL);
    int ca = 0, cb = 0;
#pragma unroll
    for (int it = 0; it < 8; ++it) {
#pragma unroll
        for (int c = 0; c < 4; ++c) {
            float vc = (c == 0) ? va[it].x : (c == 1) ? va[it].y
                     : (c == 2) ? va[it].z : va[it].w;
            u64 mm = __ballot(vc != 0.0f);
            if (vc != 0.0f) {
                int pos = ca + __popcll(mm & lmask);
                colsAll[wv][0][pos] = ((it * 256 + lane * 4 + c) << 1) | (vc < 0.0f ? 1 : 0);
            }
            ca += __popcll(mm);
        }
    }
#pragma unroll
    for (int it = 0; it < 8; ++it) {
#pragma unroll
        for (int c = 0; c < 4; ++c) {
            float vc = (c == 0) ? vb[it].x : (c == 1) ? vb[it].y
                     : (c == 2) ? vb[it].z : vb[it].w;
            u64 mm = __ballot(vc != 0.0f);
            if (vc != 0.0f) {
                int pos = cb + __popcll(mm & lmask);
                colsAll[wv][1][pos] = ((it * 256 + lane * 4 + c) << 1) | (vc < 0.0f ? 1 : 0);
            }
            cb += __popcll(mm);
        }
    }

    __syncthreads();   // a0t fully written; cols lists in LDS

    const unsigned char* a0b = (const unsigned char*)a0t;
    for (int rr = 0; rr < 2; ++rr) {
        int cnt = (rr == 0) ? ca : cb;
        int n = n0 + rr;
        const int* cols = colsAll[wv][rr];
        u32 p0=0,p1=0,p2=0,p3=0,p4=0,p5=0;
        u32 q0=0,q1=0,q2=0,q3=0,q4=0,q5=0;
#pragma unroll 8
        for (int i = 0; i < cnt; ++i) {
            int e = __builtin_amdgcn_readfirstlane(cols[i]);
            u32 m = a0b[(size_t)(e >> 1) * 64 + lane];   // LDS byte read
            if (e & 1) {   // negative (wave-uniform branch)
                u32 t;
                t = q0 & m; q0 ^= m; m = t;
                t = q1 & m; q1 ^= m; m = t;
                t = q2 & m; q2 ^= m; m = t;
                t = q3 & m; q3 ^= m; m = t;
                t = q4 & m; q4 ^= m; m = t;
                q5 ^= m;
            } else {
                u32 t;
                t = p0 & m; p0 ^= m; m = t;
                t = p1 & m; p1 ^= m; m = t;
                t = p2 & m; p2 ^= m; m = t;
                t = p3 & m; p3 ^= m; m = t;
                p5 ^= (p4 & m); p4 ^= m;
            }
        }

        u32 cand = p4 | p5;    // z>=16 requires P>=16 <=> (p4|p5) bit set
        while (cand) {
            int k = __ffs(cand) - 1;
            cand &= cand - 1;
            int P = ((p0 >> k) & 1) | (((p1 >> k) & 1) << 1) | (((p2 >> k) & 1) << 2) |
                    (((p3 >> k) & 1) << 3) | (((p4 >> k) & 1) << 4) | (((p5 >> k) & 1) << 5);
            int N = ((q0 >> k) & 1) | (((q1 >> k) & 1) << 1) | (((q2 >> k) & 1) << 2) |
                    (((q3 >> k) & 1) << 3) | (((q4 >> k) & 1) << 4) | (((q5 >> k) & 1) << 5);
            if (P - N >= THRESH) {
                int b = lane * 8 + k;
                int pos = atomicAdd(&lcnt, 1);       // LDS atomic (block-local)
                if (pos < SLOTS) pairs[bid * SLOTS + pos] = ((u32)b << 13) | (u32)n;
            }
        }
    }

    __syncthreads();
    if (tid == 0) { int c = lcnt; if (c > SLOTS) c = SLOTS; cnts[bid] = (u32)c; }
}

// Dispatch 2: one block per batch. Parallel slot-scan collection, tiny sort
// (deterministic ascending accumulation regardless of emission order),
// provably-dead layer 2 (exact W2 gather only if >=16 layer-1 actives; W2
// entries <= +1 bound z2 < 16 otherwise), Wout accumulation, logits write,
// fused argmax (numpy first-index tie-break).
__global__ __launch_bounds__(256) void out_kernel(const float* __restrict__ W2,
                                                  const float* __restrict__ Wout,
                                                  const u32* __restrict__ pairs,
                                                  const u32* __restrict__ cnts,
                                                  float* __restrict__ outp,
                                                  float* __restrict__ pred) {
    int b = blockIdx.x;
    int tid = threadIdx.x;
    __shared__ int act1[MAXACT], act2[MAXACT];
    __shared__ int n1s, n2s;
    __shared__ float rv[256];
    __shared__ int ri[256];

    if (tid == 0) { n1s = 0; n2s = 0; }
    __syncthreads();

    for (int j = tid; j < NBLK1; j += 256) {
        int c = (int)cnts[j];
        if (c > SLOTS) c = SLOTS;
        for (int i = 0; i < c; ++i) {
            u32 p = pairs[j * SLOTS + i];
            if ((int)(p >> 13) == b) {
                int pos = atomicAdd(&n1s, 1);
                if (pos < MAXACT) act1[pos] = (int)(p & 8191u);
            }
        }
    }
    __syncthreads();
    if (tid == 0) {
        int c = n1s; if (c > MAXACT) { c = MAXACT; n1s = c; }
        for (int i = 1; i < c; ++i) {                // per-batch count is tiny
            int vv = act1[i], k = i;
            while (k > 0 && act1[k - 1] > vv) { act1[k] = act1[k - 1]; --k; }
            act1[k] = vv;
        }
    }
    __syncthreads();
    int na1 = n1s;

    if (na1 >= THRESH) {
        for (int nn = tid; nn < HIDDEN; nn += 256) {
            int z = 0;
            for (int i = 0; i < na1; ++i) z += (int)W2[(size_t)nn * HIDDEN + act1[i]];
            if (z >= THRESH) {
                int pos = atomicAdd(&n2s, 1);
                if (pos < MAXACT) act2[pos] = nn;
            }
        }
        __syncthreads();
        if (tid == 0) {
            int c = n2s; if (c > MAXACT) { c = MAXACT; n2s = c; }
            for (int i = 1; i < c; ++i) {
                int vv = act2[i], k = i;
                while (k > 0 && act2[k - 1] > vv) { act2[k] = act2[k - 1]; --k; }
                act2[k] = vv;
            }
        }
        __syncthreads();
    }
    int na2 = n2s;

    float s0 = 0.f, s1 = 0.f, s2 = 0.f, s3 = 0.f;
    for (int i = 0; i < na1; ++i) {
        const float* wr = Wout + (size_t)act1[i] * CLASSES;
        s0 += wr[tid]; s1 += wr[tid + 256]; s2 += wr[tid + 512];
        if (tid + 768 < CLASSES) s3 += wr[tid + 768];
    }
    for (int i = 0; i < na2; ++i) {
        const float* wr = Wout + (size_t)HIDDEN * CLASSES + (size_t)act2[i] * CLASSES;
        s0 += wr[tid]; s1 += wr[tid + 256]; s2 += wr[tid + 512];
        if (tid + 768 < CLASSES) s3 += wr[tid + 768];
    }

    float* orow = outp + (size_t)b * CLASSES;
    orow[tid] = s0; orow[tid + 256] = s1; orow[tid + 512] = s2;
    if (tid + 768 < CLASSES) orow[tid + 768] = s3;

    float best = s0; int bi = tid;
    if (s1 > best) { best = s1; bi = tid + 256; }
    if (s2 > best) { best = s2; bi = tid + 512; }
    if (tid + 768 < CLASSES && s3 > best) { best = s3; bi = tid + 768; }
    rv[tid] = best; ri[tid] = bi;
    __syncthreads();
    for (int off = 128; off; off >>= 1) {
        if (tid < off) {
            float ov = rv[tid + off]; int oi = ri[tid + off];
            if (ov > rv[tid] || (ov == rv[tid] && oi < ri[tid])) { rv[tid] = ov; ri[tid] = oi; }
        }
        __syncthreads();
    }
    if (tid == 0) pred[b] = (float)ri[0];
}

extern "C" void kernel_launch(void* const* d_in, const int* in_sizes, int n_in,
                              void* d_out, int out_size, void* d_ws, size_t ws_size,
                              hipStream_t stream) {
    (void)in_sizes; (void)n_in; (void)out_size; (void)ws_size;
    const float* x    = (const float*)d_in[0];
    const float* W1   = (const float*)d_in[1];
    const float* W2   = (const float*)d_in[2];
    const float* Wout = (const float*)d_in[3];

    float* pred = (float*)d_out;          // 512 predictions (as float)
    float* outp = (float*)d_out + BATCH;  // 512 x 1000 logits

    char* ws = (char*)d_ws;
    u32* cnts  = (u32*)(ws + OFF_CNTS);
    u32* pairs = (u32*)(ws + OFF_PAIRS);

    z1_fused<<<NBLK1, THR1, 0, stream>>>(x, W1, cnts, pairs);
    out_kernel<<<BATCH, 256, 0, stream>>>(W2, Wout, pairs, cnts, outp, pred);
}

// Round 12
// 38.139 us; speedup vs baseline: 2.3279x; 2.3279x over previous
//
#include <hip/hip_runtime.h>

#define BATCH 512
#define FEATURES 256
#define ENC 2048
#define HIDDEN 8192
#define CLASSES 1000
#define THRESH 16
#define MAXACT 256
#define NPREP 16
#define PAIR_CAP 65536

typedef unsigned long long u64;
typedef unsigned int u32;

// -------- workspace layout (bytes) --------
// a0t    : [0, 131072)    transposed gray-code bit columns (ENC x 64 B)
// npairs : [131072]       global pair counter (zeroed by prep each launch)
// pairs  : [131136, +262144) compact (b<<13)|n list
#define OFF_A0T    0
#define OFF_NPAIRS 131072
#define OFF_PAIRS  131136

// Dispatch structure: 3 kernels, dispatch boundaries as the only cross-block
// sync. Measured on MI355X (R4-R11): every alternative is worse —
// in-kernel tree +22us, magic-gates +70us, same-line agent RMW +120us,
// acquire-poll +600us, cooperative grid.sync +475us, tiny memset node +50us,
// prep-by-redundancy +50us (13us/CU redundant VALU > 8.5us saved).

// Dispatch 1: zero npairs + build a0t. x rows staged via LDS so the HBM
// reads are coalesced.
__global__ __launch_bounds__(256) void prep_kernel(const float* __restrict__ x,
                                                   u32* __restrict__ a0t_w,
                                                   u32* __restrict__ npairs) {
    int bid = blockIdx.x;        // 32-batch word w = bid
    int tid = threadIdx.x;       // feature f = tid
    if (bid == 0 && tid == 0) npairs[0] = 0;

    __shared__ float xs[32][256];
    for (int r = 0; r < 32; ++r)
        xs[r][tid] = x[(size_t)(bid * 32 + r) * FEATURES + tid];   // coalesced
    __syncthreads();

    u32 m[8] = {0,0,0,0,0,0,0,0};
    for (int i = 0; i < 32; ++i) {
        float v = xs[i][tid];                        // 2 lanes/bank: conflict-free
        v = fminf(fmaxf(v, 0.0f), 1.0f);
        int lvl = (int)rintf(v * 255.0f);            // round-half-even == np.round
        int g = lvl ^ (lvl >> 1);
        u32 bit = 1u << i;
#pragma unroll
        for (int k = 0; k < 8; ++k) if ((g >> k) & 1) m[k] |= bit;
    }
#pragma unroll
    for (int k = 0; k < 8; ++k) a0t_w[(tid * 8 + k) * 16 + bid] = m[k];
}

// Dispatch 2: one wave per hidden-1 neuron.
//  A) preload the full 8-KB row as 8 float4 (8KB/wave in flight -> the 64 MB
//     W1 stream runs in throughput mode), ballot-compact <=32 (col,sign)
//     entries to LDS.
//  B) unroll-8 loop: scalar entry (readfirstlane) -> byte load of the 64-B
//     batch-mask line; bit-sliced carry-save counters (6 planes) for P and N.
//  Epilogue: z>=16 needs P>=16 <=> (p4|p5)!=0 -> extract only candidates.
__global__ __launch_bounds__(256) void z1_kernel(const float* __restrict__ W1,
                                                 const unsigned char* __restrict__ a0t,
                                                 u32* __restrict__ pairs,
                                                 u32* __restrict__ npairs) {
    int wid = threadIdx.x >> 6, lane = threadIdx.x & 63;
    int n = blockIdx.x * 4 + wid;
    const float4* rowv = reinterpret_cast<const float4*>(W1 + (size_t)n * ENC);
    __shared__ int colsAll[4][40];
    int* cols = colsAll[wid];

    float4 v[8];
#pragma unroll
    for (int it = 0; it < 8; ++it) v[it] = rowv[it * 64 + lane];

    int cnt = 0;
    u64 lmask = (lane == 63) ? 0x7fffffffffffffffULL : ((1ULL << lane) - 1ULL);
#pragma unroll
    for (int it = 0; it < 8; ++it) {
#pragma unroll
        for (int c = 0; c < 4; ++c) {
            float vc = (c == 0) ? v[it].x : (c == 1) ? v[it].y
                     : (c == 2) ? v[it].z : v[it].w;
            u64 mm = __ballot(vc != 0.0f);
            if (vc != 0.0f) {
                int pos = cnt + __popcll(mm & lmask);
                cols[pos] = ((it * 256 + lane * 4 + c) << 1) | (vc < 0.0f ? 1 : 0);
            }
            cnt += __popcll(mm);
        }
    }

    u32 p0=0,p1=0,p2=0,p3=0,p4=0,p5=0;
    u32 q0=0,q1=0,q2=0,q3=0,q4=0,q5=0;
#pragma unroll 8
    for (int i = 0; i < cnt; ++i) {
        int e = __builtin_amdgcn_readfirstlane(cols[i]);
        u32 m = a0t[(size_t)(e >> 1) * 64 + lane];
        if (e & 1) {   // negative (wave-uniform branch)
            u32 t;
            t = q0 & m; q0 ^= m; m = t;
            t = q1 & m; q1 ^= m; m = t;
            t = q2 & m; q2 ^= m; m = t;
            t = q3 & m; q3 ^= m; m = t;
            t = q4 & m; q4 ^= m; m = t;
            q5 ^= m;
        } else {
            u32 t;
            t = p0 & m; p0 ^= m; m = t;
            t = p1 & m; p1 ^= m; m = t;
            t = p2 & m; p2 ^= m; m = t;
            t = p3 & m; p3 ^= m; m = t;
            p5 ^= (p4 & m); p4 ^= m;
        }
    }

    u32 cand = p4 | p5;
    while (cand) {
        int k = __ffs(cand) - 1;
        cand &= cand - 1;
        int P = ((p0 >> k) & 1) | (((p1 >> k) & 1) << 1) | (((p2 >> k) & 1) << 2) |
                (((p3 >> k) & 1) << 3) | (((p4 >> k) & 1) << 4) | (((p5 >> k) & 1) << 5);
        int N = ((q0 >> k) & 1) | (((q1 >> k) & 1) << 1) | (((q2 >> k) & 1) << 2) |
                (((q3 >> k) & 1) << 3) | (((q4 >> k) & 1) << 4) | (((q5 >> k) & 1) << 5);
        if (P - N >= THRESH) {
            int b = lane * 8 + k;
            u32 pos = atomicAdd(npairs, 1u);
            if (pos < PAIR_CAP) pairs[pos] = ((u32)b << 13) | (u32)n;
        }
    }
}

// Dispatch 3: one block per batch. Parallel pair collection, tiny sort
// (deterministic ascending accumulation), provably-dead layer 2 (exact W2
// gather only if >=16 layer-1 actives; W2 entries <= +1 bound z2 < 16
// otherwise), Wout accumulation, logits write, fused argmax (numpy
// first-index tie-break).
__global__ __launch_bounds__(256) void out_kernel(const float* __restrict__ W2,
                                                  const float* __restrict__ Wout,
                                                  const u32* __restrict__ pairs,
                                                  const u32* __restrict__ npairs,
                                                  float* __restrict__ outp,
                                                  float* __restrict__ pred) {
    int b = blockIdx.x;
    int tid = threadIdx.x;
    __shared__ int act1[MAXACT], act2[MAXACT];
    __shared__ int n1s, n2s;
    __shared__ float rv[256];
    __shared__ int ri[256];

    if (tid == 0) { n1s = 0; n2s = 0; }
    __syncthreads();

    int tot = (int)npairs[0];
    if (tot > PAIR_CAP) tot = PAIR_CAP;
    for (int i = tid; i < tot; i += 256) {
        u32 p = pairs[i];
        if ((int)(p >> 13) == b) {
            int pos = atomicAdd(&n1s, 1);
            if (pos < MAXACT) act1[pos] = (int)(p & 8191u);
        }
    }
    __syncthreads();
    if (tid == 0) {
        int c = n1s; if (c > MAXACT) { c = MAXACT; n1s = c; }
        for (int i = 1; i < c; ++i) {                // per-batch count is tiny
            int vv = act1[i], k = i;
            while (k > 0 && act1[k - 1] > vv) { act1[k] = act1[k - 1]; --k; }
            act1[k] = vv;
        }
    }
    __syncthreads();
    int na1 = n1s;

    if (na1 >= THRESH) {
        for (int nn = tid; nn < HIDDEN; nn += 256) {
            int z = 0;
            for (int i = 0; i < na1; ++i) z += (int)W2[(size_t)nn * HIDDEN + act1[i]];
            if (z >= THRESH) {
                int pos = atomicAdd(&n2s, 1);
                if (pos < MAXACT) act2[pos] = nn;
            }
        }
        __syncthreads();
        if (tid == 0) {
            int c = n2s; if (c > MAXACT) { c = MAXACT; n2s = c; }
            for (int i = 1; i < c; ++i) {
                int vv = act2[i], k = i;
                while (k > 0 && act2[k - 1] > vv) { act2[k] = act2[k - 1]; --k; }
                act2[k] = vv;
            }
        }
        __syncthreads();
    }
    int na2 = n2s;

    float s0 = 0.f, s1 = 0.f, s2 = 0.f, s3 = 0.f;
    for (int i = 0; i < na1; ++i) {
        const float* wr = Wout + (size_t)act1[i] * CLASSES;
        s0 += wr[tid]; s1 += wr[tid + 256]; s2 += wr[tid + 512];
        if (tid + 768 < CLASSES) s3 += wr[tid + 768];
    }
    for (int i = 0; i < na2; ++i) {
        const float* wr = Wout + (size_t)HIDDEN * CLASSES + (size_t)act2[i] * CLASSES;
        s0 += wr[tid]; s1 += wr[tid + 256]; s2 += wr[tid + 512];
        if (tid + 768 < CLASSES) s3 += wr[tid + 768];
    }

    float* orow = outp + (size_t)b * CLASSES;
    orow[tid] = s0; orow[tid + 256] = s1; orow[tid + 512] = s2;
    if (tid + 768 < CLASSES) orow[tid + 768] = s3;

    float best = s0; int bi = tid;
    if (s1 > best) { best = s1; bi = tid + 256; }
    if (s2 > best) { best = s2; bi = tid + 512; }
    if (tid + 768 < CLASSES && s3 > best) { best = s3; bi = tid + 768; }
    rv[tid] = best; ri[tid] = bi;
    __syncthreads();
    for (int off = 128; off; off >>= 1) {
        if (tid < off) {
            float ov = rv[tid + off]; int oi = ri[tid + off];
            if (ov > rv[tid] || (ov == rv[tid] && oi < ri[tid])) { rv[tid] = ov; ri[tid] = oi; }
        }
        __syncthreads();
    }
    if (tid == 0) pred[b] = (float)ri[0];
}

extern "C" void kernel_launch(void* const* d_in, const int* in_sizes, int n_in,
                              void* d_out, int out_size, void* d_ws, size_t ws_size,
                              hipStream_t stream) {
    (void)in_sizes; (void)n_in; (void)out_size; (void)ws_size;
    const float* x    = (const float*)d_in[0];
    const float* W1   = (const float*)d_in[1];
    const float* W2   = (const float*)d_in[2];
    const float* Wout = (const float*)d_in[3];

    float* pred = (float*)d_out;          // 512 predictions (as float)
    float* outp = (float*)d_out + BATCH;  // 512 x 1000 logits

    char* ws = (char*)d_ws;
    u32* a0t_w  = (u32*)(ws + OFF_A0T);
    u32* npairs = (u32*)(ws + OFF_NPAIRS);
    u32* pairs  = (u32*)(ws + OFF_PAIRS);

    prep_kernel<<<NPREP, 256, 0, stream>>>(x, a0t_w, npairs);
    z1_kernel<<<HIDDEN / 4, 256, 0, stream>>>(W1, (const unsigned char*)a0t_w,
                                              pairs, npairs);
    out_kernel<<<BATCH, 256, 0, stream>>>(W2, Wout, pairs, npairs, outp, pred);
}